// Round 5
// baseline (525.271 us; speedup 1.0000x reference)
//
#include <hip/hip_runtime.h>
#include <hip/hip_bf16.h>
#include <cstdint>
#include <cstddef>

using bf16 = __hip_bfloat16;
typedef __attribute__((ext_vector_type(8))) short short8;
typedef __attribute__((ext_vector_type(4))) short short4v;
typedef __attribute__((ext_vector_type(4))) float f32x4;

#define MFMA16(a,b,c) __builtin_amdgcn_mfma_f32_16x16x32_bf16((a),(b),(c),0,0,0)
#define VMWAIT(n) asm volatile("s_waitcnt vmcnt(" #n ")" ::: "memory")

constexpr int S  = 2048;
constexpr int H  = 4096;
constexpr int D  = 128;

static __device__ __forceinline__ short bfbits(float f) {
  bf16 b = __float2bfloat16(f);
  return __builtin_bit_cast(short, b);
}

static __device__ __forceinline__ void gload16(const void* g, void* l) {
  __builtin_amdgcn_global_load_lds((const __attribute__((address_space(1))) void*)g,
                                   (__attribute__((address_space(3))) void*)l, 16, 0, 0);
}

// ---------------- RoPE cos/sin table: [S][64] float2 ----------------
__global__ void k_rope_table(float2* __restrict__ rt) {
  int tid = blockIdx.x * 256 + threadIdx.x;     // S*64 = 131072
  if (tid >= S * 64) return;
  int s = tid >> 6, j = tid & 63;
  float inv = exp2f(-(float)j * (13.287712379549449f / 64.f)); // 10000^(-j/64)
  float a = (float)s * inv;
  rt[tid] = make_float2(cosf(a), sinf(a));
}

// ---------------- cast hidden fp32 -> bf16 ----------------
__global__ void k_cast_x(const float4* __restrict__ x, short4v* __restrict__ xb) {
  int tid = blockIdx.x * 256 + threadIdx.x;     // S*H/4
  float4 v = x[tid];
  short4v o = { bfbits(v.x), bfbits(v.y), bfbits(v.z), bfbits(v.w) };
  xb[tid] = o;
}

// ---------------- GPTQ int4 dequant -> W^T bf16 [N][K] ----------------
__global__ void k_dequant(const unsigned* __restrict__ qw, const unsigned* __restrict__ qz,
                          const float* __restrict__ sc, bf16* __restrict__ wt,
                          int N, int K) {
  long tid = (long)blockIdx.x * 256 + threadIdx.x;   // over (K/8) * N
  if (tid >= (long)(K >> 3) * N) return;
  int k8 = (int)(tid / N);
  int n  = (int)(tid % N);
  int g  = k8 >> 4;                      // (k8*8)/128
  unsigned q  = qw[tid];                 // qweight[k8][n]
  unsigned zq = qz[g * (N >> 3) + (n >> 3)];
  float z = (float)(((zq >> ((n & 7) * 4)) & 15u) + 1u);
  float s = sc[g * N + n];
  short8 o;
#pragma unroll
  for (int i = 0; i < 8; i++) {
    float w = (float)((q >> (4 * i)) & 15u);
    o[i] = bfbits((w - z) * s);
  }
  *(short8*)&wt[(size_t)n * K + (k8 << 3)] = o;
}

// ---------------- bf16 MFMA GEMM, big wave tiles + swizzled LDS ----------------
// C[M,N] = A[M,K] @ Bt[N,K]^T.  BM=128, BK=32, 256 thr = 4 waves.
// Wave tile = (128/WM) x 128. Triple-buffered LDS, lookahead 2, counted vmcnt.
// LDS chunk-XOR swizzle: global source chunk pre-swizzled (gload_lds dest must
// stay linear); read-side XOR is lane-constant (frag rows 16-aligned).
template<int EPI, int BN>
__global__ __launch_bounds__(256, 2)
void k_gemm2(const bf16* __restrict__ A, const bf16* __restrict__ Bt, int K, int N,
             float* __restrict__ outf,
             bf16* __restrict__ Qv, bf16* __restrict__ Kv, bf16* __restrict__ VT,
             const float2* __restrict__ rope, int nby)
{
  constexpr int WN     = BN / 128;     // wave-columns (1 or 2)
  constexpr int WM     = 4 / WN;       // wave-rows
  constexpr int RWM    = 128 / WM;     // rows per wave
  constexpr int MF     = RWM / 16;     // m-frags per wave
  constexpr int BLOADS = BN / 64;      // B stage loads per thread
  constexpr int TL     = 2 + BLOADS;   // loads per stage (6 or 4)

  __shared__ __align__(16) bf16 sA[3][128 * 32];
  __shared__ __align__(16) bf16 sB[3][BN * 32];

  const int t = threadIdx.x;
  const int wid = t >> 6, lane = t & 63;
  const int la = lane & 15, lb = lane >> 4;
  const int wr = wid / WN, wc = wid % WN;

  const int nwg  = gridDim.x;
  const int bid  = blockIdx.x;
  const int wgid = (bid & 7) * (nwg >> 3) + (bid >> 3);   // bijective (nwg%8==0)
  const int by = wgid % nby, bx = wgid / nby;             // col-major: B-panel L2-resident
  const int m0 = by * 128, n0 = bx * BN;

  // staging: thread t covers row (j*64 + t>>2), LDS chunk t&3; global chunk
  // is pre-swizzled so LDS[row][c'] = global[row][c' ^ ((row>>1)&3)].
  const int cswz = ((t & 3) ^ ((t >> 3) & 3)) * 8;        // elements
  const bf16* gA0 = A  + (size_t)(m0 + (t >> 2)) * K + cswz;
  const bf16* gB0 = Bt + (size_t)(n0 + (t >> 2)) * K + cswz;

  const int NT = K >> 5;

  auto stage = [&](int tile, int buf) {
    const bf16* a = gA0 + tile * 32;
#pragma unroll
    for (int j = 0; j < 2; j++)
      gload16(a + (size_t)j * 64 * K, (bf16*)&sA[buf][0] + j * 2048 + t * 8);
    const bf16* b = gB0 + tile * 32;
#pragma unroll
    for (int j = 0; j < BLOADS; j++)
      gload16(b + (size_t)j * 64 * K, (bf16*)&sB[buf][0] + j * 2048 + t * 8);
  };

  f32x4 acc[MF][8] = {};

  stage(0, 0); stage(1, 1);
  if constexpr (BN == 256) VMWAIT(6); else VMWAIT(4);     // tile 0 landed
  __builtin_amdgcn_s_barrier();

  const char* cA = (const char*)&sA[0][0];
  const char* cB = (const char*)&sB[0][0];
  const int rcol  = (lb ^ ((la >> 1) & 3)) << 4;          // lane-constant read swizzle
  const int arow0 = wr * RWM + la;
  const int brow0 = wc * 128 + la;

  int b0 = 0, b1 = 1, b2 = 2;
  for (int tt = 0; tt < NT; tt++) {
    if (tt + 2 < NT) stage(tt + 2, b2);
    const char* bufA = cA + b0 * 8192;
    const char* bufB = cB + b0 * (BN * 64);
    short8 af[MF], bfr[8];
#pragma unroll
    for (int mf = 0; mf < MF; mf++)
      af[mf] = *(const short8*)(bufA + (arow0 + mf * 16) * 64 + rcol);
#pragma unroll
    for (int nf = 0; nf < 8; nf++)
      bfr[nf] = *(const short8*)(bufB + (brow0 + nf * 16) * 64 + rcol);
    __builtin_amdgcn_s_setprio(1);
#pragma unroll
    for (int mf = 0; mf < MF; mf++)
#pragma unroll
      for (int nf = 0; nf < 8; nf++)
        acc[mf][nf] = MFMA16(af[mf], bfr[nf], acc[mf][nf]);
    __builtin_amdgcn_s_setprio(0);
    asm volatile("s_waitcnt lgkmcnt(0)" ::: "memory");    // ds_reads retired
    if (tt + 2 < NT)      { if constexpr (BN == 256) VMWAIT(6); else VMWAIT(4); }
    else if (tt + 1 < NT) VMWAIT(0);
    __builtin_amdgcn_s_barrier();
    int tmp = b0; b0 = b1; b1 = b2; b2 = tmp;
  }

  if constexpr (EPI == 1) {
#pragma unroll
    for (int mf = 0; mf < MF; mf++)
#pragma unroll
      for (int nf = 0; nf < 8; nf++)
#pragma unroll
        for (int r = 0; r < 4; r++) {
          int row = m0 + wr * RWM + mf * 16 + lb * 4 + r;
          int col = n0 + wc * 128 + nf * 16 + la;
          outf[(size_t)row * N + col] = acc[mf][nf][r];
        }
  } else {
    const int nbase = n0 + wc * 128;          // 128-aligned => exactly one head
    const int typ = nbase >> 12;              // 0=q, 1=k, 2=v
    const int h   = (nbase & 4095) >> 7;
    if (typ < 2) {
      bf16* dst = (typ == 0 ? Qv : Kv) + (size_t)h * S * D;
#pragma unroll
      for (int mf = 0; mf < MF; mf++)
#pragma unroll
        for (int nf = 0; nf < 4; nf++)
#pragma unroll
          for (int r = 0; r < 4; r++) {
            int srow = m0 + wr * RWM + mf * 16 + lb * 4 + r;
            int d = nf * 16 + la;                       // 0..63
            float x  = acc[mf][nf][r];
            float xp = acc[mf][nf + 4][r];              // d+64 partner
            float2 cs = rope[srow * 64 + d];
            dst[(size_t)srow * D + d]      = __float2bfloat16(x * cs.x - xp * cs.y);
            dst[(size_t)srow * D + d + 64] = __float2bfloat16(xp * cs.x + x * cs.y);
          }
    } else {
      bf16* dst = VT + (size_t)h * D * S;   // [d][s]
#pragma unroll
      for (int mf = 0; mf < MF; mf++)
#pragma unroll
        for (int nf = 0; nf < 8; nf++) {
          int d  = nf * 16 + la;
          int s0 = m0 + wr * RWM + mf * 16 + lb * 4;
          short4v o = { bfbits(acc[mf][nf][0]), bfbits(acc[mf][nf][1]),
                        bfbits(acc[mf][nf][2]), bfbits(acc[mf][nf][3]) };
          *(short4v*)&dst[(size_t)d * S + s0] = o;
        }
    }
  }
}

// ---------------- causal flash attention, paired q-tiles + LDS KV pipeline ----
__device__ __forceinline__ void tile_step(
    const short8 (&qf)[4], f32x4 (&o)[8], float (&mrow)[4], float (&lrow)[4],
    int q0t, int kv0, const char* kld, const char* vld,
    bf16 (*Pw)[72], int la, int lb)
{
  const float smscale = 0.08838834764831845f;   // 1/sqrt(128)
  f32x4 sv[4] = {};
  __builtin_amdgcn_s_setprio(1);
#pragma unroll
  for (int ks = 0; ks < 4; ks++) {
#pragma unroll
    for (int kf = 0; kf < 4; kf++) {
      int row = kf * 16 + la;
      short8 kb = *(const short8*)(kld + row * 256 + ((ks * 64 + lb * 16) ^ ((row & 7) << 4)));
      sv[kf] = MFMA16(qf[ks], kb, sv[kf]);
    }
  }
  __builtin_amdgcn_s_setprio(0);
  const bool needmask = (kv0 + 63 > q0t);
#pragma unroll
  for (int kf = 0; kf < 4; kf++)
#pragma unroll
    for (int r = 0; r < 4; r++) {
      float v = sv[kf][r] * smscale;
      if (needmask && (kv0 + kf * 16 + la > q0t + lb * 4 + r)) v = -1e30f;
      sv[kf][r] = v;
    }
  float mnew[4], csc[4], rs[4];
#pragma unroll
  for (int r = 0; r < 4; r++)
    mnew[r] = fmaxf(fmaxf(sv[0][r], sv[1][r]), fmaxf(sv[2][r], sv[3][r]));
#pragma unroll
  for (int off = 1; off < 16; off <<= 1)
#pragma unroll
    for (int r = 0; r < 4; r++) mnew[r] = fmaxf(mnew[r], __shfl_xor(mnew[r], off));
#pragma unroll
  for (int r = 0; r < 4; r++) {
    float mt = fmaxf(mrow[r], mnew[r]);
    csc[r] = __expf(mrow[r] - mt);
    mrow[r] = mt;
    rs[r] = 0.f;
  }
#pragma unroll
  for (int kf = 0; kf < 4; kf++)
#pragma unroll
    for (int r = 0; r < 4; r++) {
      float p = __expf(sv[kf][r] - mrow[r]);
      sv[kf][r] = p;
      rs[r] += p;
    }
#pragma unroll
  for (int off = 1; off < 16; off <<= 1)
#pragma unroll
    for (int r = 0; r < 4; r++) rs[r] += __shfl_xor(rs[r], off);
#pragma unroll
  for (int r = 0; r < 4; r++) lrow[r] = lrow[r] * csc[r] + rs[r];
#pragma unroll
  for (int df = 0; df < 8; df++)
#pragma unroll
    for (int r = 0; r < 4; r++) o[df][r] *= csc[r];
#pragma unroll
  for (int kf = 0; kf < 4; kf++)
#pragma unroll
    for (int r = 0; r < 4; r++)
      Pw[lb * 4 + r][kf * 16 + la] = __float2bfloat16(sv[kf][r]);
  asm volatile("s_waitcnt lgkmcnt(0)" ::: "memory");
  __builtin_amdgcn_sched_barrier(0);
  short8 pa0 = *(const short8*)&Pw[la][lb * 8];
  short8 pa1 = *(const short8*)&Pw[la][32 + lb * 8];
  __builtin_amdgcn_s_setprio(1);
#pragma unroll
  for (int df = 0; df < 8; df++) {
    int d = df * 16 + la;
    short8 vb0 = *(const short8*)(vld + d * 128 + ((lb * 16) ^ ((d & 7) << 4)));
    o[df] = MFMA16(pa0, vb0, o[df]);
    short8 vb1 = *(const short8*)(vld + d * 128 + ((64 + lb * 16) ^ ((d & 7) << 4)));
    o[df] = MFMA16(pa1, vb1, o[df]);
  }
  __builtin_amdgcn_s_setprio(0);
}

__global__ __launch_bounds__(256, 2)
void k_attn(const bf16* __restrict__ Qv, const bf16* __restrict__ Kvp,
            const bf16* __restrict__ VT, bf16* __restrict__ AO)
{
  __shared__ __align__(16) char kvs[2][2][16384];   // [dbuf][K/V]
  __shared__ __align__(16) bf16 P[4][16][72];
  const int t = threadIdx.x, wid = t >> 6, lane = t & 63;
  const int la = lane & 15, lb = lane >> 4;
  const int h = blockIdx.y, ip = blockIdx.x;         // 0..15
  const int tA = ip, tB = 31 - ip;
  const int q0A = tA * 64 + wid * 16, q0B = tB * 64 + wid * 16;
  const bf16* Qh = Qv  + (size_t)h * S * D;
  const bf16* Kh = Kvp + (size_t)h * S * D;
  const bf16* Vh = VT  + (size_t)h * D * S;

  short8 qfA[4], qfB[4];
#pragma unroll
  for (int ks = 0; ks < 4; ks++) {
    qfA[ks] = *(const short8*)&Qh[(size_t)(q0A + la) * D + ks * 32 + lb * 8];
    qfB[ks] = *(const short8*)&Qh[(size_t)(q0B + la) * D + ks * 32 + lb * 8];
  }

  f32x4 oA[8] = {}, oB[8] = {};
  float mA[4] = {-1e30f, -1e30f, -1e30f, -1e30f}, lA[4] = {};
  float mB[4] = {-1e30f, -1e30f, -1e30f, -1e30f}, lB[4] = {};

  auto stage = [&](int buf, int kv0) {
#pragma unroll
    for (int i = 0; i < 4; i++) {
      int off = i * 4096 + wid * 1024 + lane * 16;
      int krow = off >> 8, kcol = off & 255;
      const char* ksrc = (const char*)Kh + (size_t)(kv0 + krow) * 256 + (kcol ^ ((krow & 7) << 4));
      gload16(ksrc, &kvs[buf][0][i * 4096 + wid * 1024]);
      int vrow = off >> 7, vcol = off & 127;
      const char* vsrc = (const char*)Vh + (size_t)vrow * (S * 2) + kv0 * 2 + (vcol ^ ((vrow & 7) << 4));
      gload16(vsrc, &kvs[buf][1][i * 4096 + wid * 1024]);
    }
  };

  stage(0, 0);
  __syncthreads();

  const int last = tB;
  for (int kt = 0; kt <= last; kt++) {
    int cur = kt & 1;
    if (kt < last) stage(cur ^ 1, (kt + 1) * 64);
    const char* kld = kvs[cur][0];
    const char* vld = kvs[cur][1];
    int kv0 = kt * 64;
    if (kt <= tA) tile_step(qfA, oA, mA, lA, q0A, kv0, kld, vld, P[wid], la, lb);
    tile_step(qfB, oB, mB, lB, q0B, kv0, kld, vld, P[wid], la, lb);
    __syncthreads();
  }

#pragma unroll
  for (int r = 0; r < 4; r++) { mA[r] = 1.f / lA[r]; mB[r] = 1.f / lB[r]; }
#pragma unroll
  for (int df = 0; df < 8; df++)
#pragma unroll
    for (int r = 0; r < 4; r++) {
      int d = df * 16 + la;
      AO[(size_t)(q0A + lb * 4 + r) * H + h * D + d] = __float2bfloat16(oA[df][r] * mA[r]);
      AO[(size_t)(q0B + lb * 4 + r) * H + h * D + d] = __float2bfloat16(oB[df][r] * mB[r]);
    }
}

extern "C" void kernel_launch(void* const* d_in, const int* in_sizes, int n_in,
                              void* d_out, int out_size, void* d_ws, size_t ws_size,
                              hipStream_t stream) {
  const float*    X      = (const float*)d_in[0];
  const unsigned* qw_qkv = (const unsigned*)d_in[1];
  const unsigned* qz_qkv = (const unsigned*)d_in[2];
  const float*    sc_qkv = (const float*)d_in[3];
  const unsigned* qw_o   = (const unsigned*)d_in[4];
  const unsigned* qz_o   = (const unsigned*)d_in[5];
  const float*    sc_o   = (const float*)d_in[6];
  float* out = (float*)d_out;

  if (ws_size < 168820736ULL) return;
  char* ws = (char*)d_ws;
  bf16*   Wt = (bf16*)(ws);
  bf16*   Xb = (bf16*)(ws + 100663296);
  bf16*   Qv = (bf16*)(ws + 117440512);
  bf16*   Kv = (bf16*)(ws + 134217728);
  bf16*   VT = (bf16*)(ws + 150994944);
  float2* rt = (float2*)(ws + 167772160);
  bf16*   AO = Xb;

  k_rope_table<<<512, 256, 0, stream>>>(rt);
  k_cast_x<<<(S * H / 4) / 256, 256, 0, stream>>>((const float4*)X, (short4v*)Xb);
  k_dequant<<<(512 * 12288) / 256, 256, 0, stream>>>(qw_qkv, qz_qkv, sc_qkv, Wt, 12288, 4096);
  k_gemm2<0, 256><<<768, 256, 0, stream>>>(Xb, Wt, 4096, 12288, nullptr, Qv, Kv, VT, rt, 16);
  k_dequant<<<(512 * 4096) / 256, 256, 0, stream>>>(qw_o, qz_o, sc_o, Wt, 4096, 4096);
  k_attn<<<dim3(16, 32), 256, 0, stream>>>(Qv, Kv, VT, AO);
  k_gemm2<1, 128><<<512, 256, 0, stream>>>(AO, Wt, 4096, 4096, out, nullptr, nullptr, nullptr, nullptr, 16);
}

// Round 6
// 461.114 us; speedup vs baseline: 1.1391x; 1.1391x over previous
//
#include <hip/hip_runtime.h>
#include <hip/hip_bf16.h>
#include <cstdint>
#include <cstddef>

using bf16 = __hip_bfloat16;
typedef __attribute__((ext_vector_type(8))) short short8;
typedef __attribute__((ext_vector_type(4))) short short4v;
typedef __attribute__((ext_vector_type(4))) float f32x4;

#define MFMA16(a,b,c) __builtin_amdgcn_mfma_f32_16x16x32_bf16((a),(b),(c),0,0,0)
#define VMWAIT(n) asm volatile("s_waitcnt vmcnt(" #n ")" ::: "memory")

constexpr int S  = 2048;
constexpr int H  = 4096;
constexpr int D  = 128;

static __device__ __forceinline__ short bfbits(float f) {
  bf16 b = __float2bfloat16(f);
  return __builtin_bit_cast(short, b);
}

static __device__ __forceinline__ void gload16(const void* g, void* l) {
  __builtin_amdgcn_global_load_lds((const __attribute__((address_space(1))) void*)g,
                                   (__attribute__((address_space(3))) void*)l, 16, 0, 0);
}

// ---------------- RoPE cos/sin table: [S][64] float2 ----------------
__global__ void k_rope_table(float2* __restrict__ rt) {
  int tid = blockIdx.x * 256 + threadIdx.x;     // S*64 = 131072
  if (tid >= S * 64) return;
  int s = tid >> 6, j = tid & 63;
  float inv = exp2f(-(float)j * (13.287712379549449f / 64.f)); // 10000^(-j/64)
  float a = (float)s * inv;
  rt[tid] = make_float2(cosf(a), sinf(a));
}

// ---------------- cast hidden fp32 -> bf16 ----------------
__global__ void k_cast_x(const float4* __restrict__ x, short4v* __restrict__ xb) {
  int tid = blockIdx.x * 256 + threadIdx.x;     // S*H/4
  float4 v = x[tid];
  short4v o = { bfbits(v.x), bfbits(v.y), bfbits(v.z), bfbits(v.w) };
  xb[tid] = o;
}

// ---------------- GPTQ int4 dequant -> W^T bf16 [N][K] ----------------
__global__ void k_dequant(const unsigned* __restrict__ qw, const unsigned* __restrict__ qz,
                          const float* __restrict__ sc, bf16* __restrict__ wt,
                          int N, int K) {
  long tid = (long)blockIdx.x * 256 + threadIdx.x;   // over (K/8) * N
  if (tid >= (long)(K >> 3) * N) return;
  int k8 = (int)(tid / N);
  int n  = (int)(tid % N);
  int g  = k8 >> 4;                      // (k8*8)/128
  unsigned q  = qw[tid];                 // qweight[k8][n]
  unsigned zq = qz[g * (N >> 3) + (n >> 3)];
  float z = (float)(((zq >> ((n & 7) * 4)) & 15u) + 1u);
  float s = sc[g * N + n];
  short8 o;
#pragma unroll
  for (int i = 0; i < 8; i++) {
    float w = (float)((q >> (4 * i)) & 15u);
    o[i] = bfbits((w - z) * s);
  }
  *(short8*)&wt[(size_t)n * K + (k8 << 3)] = o;
}

// ---------------- phase-interleaved bf16 MFMA GEMM ----------------
// C[M,N] = A[M,K] @ Bt[N,K]^T.  BM=256, BN=128, BK=64, 512 thr = 8 waves
// (4 wr x 2 wc), wave tile 64x64.  3 LDS buffers (144 KB), prefetch depth
// 2 K-tiles.  2 phases per K-tile, each: 8 ds_read_b128 + 3 gload_lds ->
// barrier -> lgkmcnt(0) -> 16 MFMA -> barrier; vmcnt(6) once per K-tile.
// LDS chunk-XOR swizzle (row&7) with inverse applied to global source.
template<int EPI>
__global__ __launch_bounds__(512, 2)
void k_gemm8(const bf16* __restrict__ A, const bf16* __restrict__ Bt, int K, int N,
             float* __restrict__ outf,
             bf16* __restrict__ Qv, bf16* __restrict__ Kv, bf16* __restrict__ VT,
             const float2* __restrict__ rope, int nby)
{
  __shared__ __align__(16) bf16 sA[3][256 * 64];   // 96 KB
  __shared__ __align__(16) bf16 sB[3][128 * 64];   // 48 KB

  const int t = threadIdx.x;
  const int wid = t >> 6, lane = t & 63;
  const int la = lane & 15, lb = lane >> 4;
  const int wr = wid >> 1, wc = wid & 1;

  const int nwg  = gridDim.x;
  const int bid  = blockIdx.x;
  const int wgid = (bid & 7) * (nwg >> 3) + (bid >> 3);   // bijective (nwg%8==0)
  const int by = wgid % nby, bx = wgid / nby;             // col-major: B-panel sharing
  const int m0 = by * 256, n0 = bx * 128;

  // staging: thread t covers row (t>>3) of a 64-row group, 16B chunk (t&7);
  // global chunk pre-swizzled by row&7 so LDS stays linear for gload_lds.
  const int srow = t >> 3;
  const int scol = ((t & 7) ^ (srow & 7)) * 8;            // element offset
  const bf16* gA = A  + (size_t)(m0 + srow) * K + scol;
  const bf16* gB = Bt + (size_t)(n0 + srow) * K + scol;

  const int NT = K >> 6;                                  // BK=64

  auto stage = [&](int tile, int buf, int ph) {
    const bf16* a = gA + tile * 64 + (size_t)(ph * 128) * K;
    gload16(a,                  &sA[buf][ph * 8192] + t * 8);
    gload16(a + (size_t)64 * K, &sA[buf][ph * 8192 + 4096] + t * 8);
    const bf16* b = gB + tile * 64 + (size_t)(ph * 64) * K;
    gload16(b, &sB[buf][ph * 4096] + t * 8);
  };

  f32x4 acc[4][4] = {};

  stage(0, 0, 0); stage(0, 0, 1);
  stage(1, 1, 0); stage(1, 1, 1);
  VMWAIT(6);                                 // tile 0 landed
  __builtin_amdgcn_s_barrier();

  const char* const cA = (const char*)&sA[0][0];
  const char* const cB = (const char*)&sB[0][0];

  for (int tt = 0; tt < NT; tt++) {
    const int cb = tt % 3;
    const int pb = (tt + 2) % 3;
    const char* bA = cA + cb * 32768;
    const char* bB = cB + cb * 16384;
#pragma unroll
    for (int ph = 0; ph < 2; ph++) {
      const int colb = ((ph * 4 + lb) ^ (la & 7)) * 16;   // swizzled 16B slot
      short8 af[4], bfr[4];
#pragma unroll
      for (int mf = 0; mf < 4; mf++)
        af[mf] = *(const short8*)(bA + (wr * 64 + mf * 16 + la) * 128 + colb);
#pragma unroll
      for (int nf = 0; nf < 4; nf++)
        bfr[nf] = *(const short8*)(bB + (wc * 64 + nf * 16 + la) * 128 + colb);
      if (tt + 2 < NT) stage(tt + 2, pb, ph);
      __builtin_amdgcn_sched_barrier(0);
      __builtin_amdgcn_s_barrier();
      asm volatile("s_waitcnt lgkmcnt(0)" ::: "memory");
      __builtin_amdgcn_sched_barrier(0);
      __builtin_amdgcn_s_setprio(1);
#pragma unroll
      for (int mf = 0; mf < 4; mf++)
#pragma unroll
        for (int nf = 0; nf < 4; nf++)
          acc[mf][nf] = MFMA16(af[mf], bfr[nf], acc[mf][nf]);
      __builtin_amdgcn_s_setprio(0);
      if (ph == 1) {
        if (tt + 2 < NT)      VMWAIT(6);    // next tile fully landed
        else if (tt + 1 < NT) VMWAIT(0);    // drain final tile
      }
      __builtin_amdgcn_s_barrier();
    }
  }

  if constexpr (EPI == 1) {
#pragma unroll
    for (int mf = 0; mf < 4; mf++)
#pragma unroll
      for (int nf = 0; nf < 4; nf++)
#pragma unroll
        for (int r = 0; r < 4; r++) {
          int row = m0 + wr * 64 + mf * 16 + lb * 4 + r;
          int col = n0 + wc * 64 + nf * 16 + la;
          outf[(size_t)row * N + col] = acc[mf][nf][r];
        }
  } else {
    const int typ = n0 >> 12;              // block = exactly one 128-col head
    const int h   = (n0 & 4095) >> 7;
    if (typ == 2) {
      bf16* dst = VT + (size_t)h * D * S;  // [d][s]
#pragma unroll
      for (int mf = 0; mf < 4; mf++)
#pragma unroll
        for (int nf = 0; nf < 4; nf++) {
          int d  = wc * 64 + nf * 16 + la;
          int s0 = m0 + wr * 64 + mf * 16 + lb * 4;
          short4v o = { bfbits(acc[mf][nf][0]), bfbits(acc[mf][nf][1]),
                        bfbits(acc[mf][nf][2]), bfbits(acc[mf][nf][3]) };
          *(short4v*)&dst[(size_t)d * S + s0] = o;
        }
    } else {
      // RoPE needs (d, d+64) pairs which live in different waves:
      // exchange the whole 256x128 tile through the (now free) staging LDS.
      bf16* dst = (typ == 0 ? Qv : Kv) + (size_t)h * S * D;
      bf16* xs = (bf16*)&sA[0][0];         // [256][128] bf16 = 64 KB
      __syncthreads();
#pragma unroll
      for (int mf = 0; mf < 4; mf++)
#pragma unroll
        for (int nf = 0; nf < 4; nf++)
#pragma unroll
          for (int r = 0; r < 4; r++)
            xs[(wr * 64 + mf * 16 + lb * 4 + r) * 128 + wc * 64 + nf * 16 + la] =
                __float2bfloat16(acc[mf][nf][r]);
      __syncthreads();
#pragma unroll 4
      for (int w = 0; w < 32; w++) {
        int idx = w * 512 + t;             // 256 rows x 64 d-pairs
        int row = idx >> 6, dp = idx & 63;
        float x  = __bfloat162float(xs[row * 128 + dp]);
        float xp = __bfloat162float(xs[row * 128 + dp + 64]);
        float2 cs = rope[(size_t)(m0 + row) * 64 + dp];
        dst[(size_t)(m0 + row) * D + dp]      = __float2bfloat16(x * cs.x - xp * cs.y);
        dst[(size_t)(m0 + row) * D + dp + 64] = __float2bfloat16(xp * cs.x + x * cs.y);
      }
    }
  }
}

// ---------------- causal flash attention, paired q-tiles + LDS KV pipeline ----
__device__ __forceinline__ void tile_step(
    const short8 (&qf)[4], f32x4 (&o)[8], float (&mrow)[4], float (&lrow)[4],
    int q0t, int kv0, const char* kld, const char* vld,
    bf16 (*Pw)[72], int la, int lb)
{
  const float smscale = 0.08838834764831845f;   // 1/sqrt(128)
  f32x4 sv[4] = {};
  __builtin_amdgcn_s_setprio(1);
#pragma unroll
  for (int ks = 0; ks < 4; ks++) {
#pragma unroll
    for (int kf = 0; kf < 4; kf++) {
      int row = kf * 16 + la;
      short8 kb = *(const short8*)(kld + row * 256 + ((ks * 64 + lb * 16) ^ ((row & 7) << 4)));
      sv[kf] = MFMA16(qf[ks], kb, sv[kf]);
    }
  }
  __builtin_amdgcn_s_setprio(0);
  const bool needmask = (kv0 + 63 > q0t);
#pragma unroll
  for (int kf = 0; kf < 4; kf++)
#pragma unroll
    for (int r = 0; r < 4; r++) {
      float v = sv[kf][r] * smscale;
      if (needmask && (kv0 + kf * 16 + la > q0t + lb * 4 + r)) v = -1e30f;
      sv[kf][r] = v;
    }
  float mnew[4], csc[4], rs[4];
#pragma unroll
  for (int r = 0; r < 4; r++)
    mnew[r] = fmaxf(fmaxf(sv[0][r], sv[1][r]), fmaxf(sv[2][r], sv[3][r]));
#pragma unroll
  for (int off = 1; off < 16; off <<= 1)
#pragma unroll
    for (int r = 0; r < 4; r++) mnew[r] = fmaxf(mnew[r], __shfl_xor(mnew[r], off));
#pragma unroll
  for (int r = 0; r < 4; r++) {
    float mt = fmaxf(mrow[r], mnew[r]);
    csc[r] = __expf(mrow[r] - mt);
    mrow[r] = mt;
    rs[r] = 0.f;
  }
#pragma unroll
  for (int kf = 0; kf < 4; kf++)
#pragma unroll
    for (int r = 0; r < 4; r++) {
      float p = __expf(sv[kf][r] - mrow[r]);
      sv[kf][r] = p;
      rs[r] += p;
    }
#pragma unroll
  for (int off = 1; off < 16; off <<= 1)
#pragma unroll
    for (int r = 0; r < 4; r++) rs[r] += __shfl_xor(rs[r], off);
#pragma unroll
  for (int r = 0; r < 4; r++) lrow[r] = lrow[r] * csc[r] + rs[r];
#pragma unroll
  for (int df = 0; df < 8; df++)
#pragma unroll
    for (int r = 0; r < 4; r++) o[df][r] *= csc[r];
#pragma unroll
  for (int kf = 0; kf < 4; kf++)
#pragma unroll
    for (int r = 0; r < 4; r++)
      Pw[lb * 4 + r][kf * 16 + la] = __float2bfloat16(sv[kf][r]);
  asm volatile("s_waitcnt lgkmcnt(0)" ::: "memory");
  __builtin_amdgcn_sched_barrier(0);
  short8 pa0 = *(const short8*)&Pw[la][lb * 8];
  short8 pa1 = *(const short8*)&Pw[la][32 + lb * 8];
  __builtin_amdgcn_s_setprio(1);
#pragma unroll
  for (int df = 0; df < 8; df++) {
    int d = df * 16 + la;
    short8 vb0 = *(const short8*)(vld + d * 128 + ((lb * 16) ^ ((d & 7) << 4)));
    o[df] = MFMA16(pa0, vb0, o[df]);
    short8 vb1 = *(const short8*)(vld + d * 128 + ((64 + lb * 16) ^ ((d & 7) << 4)));
    o[df] = MFMA16(pa1, vb1, o[df]);
  }
  __builtin_amdgcn_s_setprio(0);
}

__global__ __launch_bounds__(256, 2)
void k_attn(const bf16* __restrict__ Qv, const bf16* __restrict__ Kvp,
            const bf16* __restrict__ VT, bf16* __restrict__ AO)
{
  __shared__ __align__(16) char kvs[2][2][16384];   // [dbuf][K/V]
  __shared__ __align__(16) bf16 P[4][16][72];
  const int t = threadIdx.x, wid = t >> 6, lane = t & 63;
  const int la = lane & 15, lb = lane >> 4;
  const int h = blockIdx.y, ip = blockIdx.x;         // 0..15
  const int tA = ip, tB = 31 - ip;
  const int q0A = tA * 64 + wid * 16, q0B = tB * 64 + wid * 16;
  const bf16* Qh = Qv  + (size_t)h * S * D;
  const bf16* Kh = Kvp + (size_t)h * S * D;
  const bf16* Vh = VT  + (size_t)h * D * S;

  short8 qfA[4], qfB[4];
#pragma unroll
  for (int ks = 0; ks < 4; ks++) {
    qfA[ks] = *(const short8*)&Qh[(size_t)(q0A + la) * D + ks * 32 + lb * 8];
    qfB[ks] = *(const short8*)&Qh[(size_t)(q0B + la) * D + ks * 32 + lb * 8];
  }

  f32x4 oA[8] = {}, oB[8] = {};
  float mA[4] = {-1e30f, -1e30f, -1e30f, -1e30f}, lA[4] = {};
  float mB[4] = {-1e30f, -1e30f, -1e30f, -1e30f}, lB[4] = {};

  auto stage = [&](int buf, int kv0) {
#pragma unroll
    for (int i = 0; i < 4; i++) {
      int off = i * 4096 + wid * 1024 + lane * 16;
      int krow = off >> 8, kcol = off & 255;
      const char* ksrc = (const char*)Kh + (size_t)(kv0 + krow) * 256 + (kcol ^ ((krow & 7) << 4));
      gload16(ksrc, &kvs[buf][0][i * 4096 + wid * 1024]);
      int vrow = off >> 7, vcol = off & 127;
      const char* vsrc = (const char*)Vh + (size_t)vrow * (S * 2) + kv0 * 2 + (vcol ^ ((vrow & 7) << 4));
      gload16(vsrc, &kvs[buf][1][i * 4096 + wid * 1024]);
    }
  };

  stage(0, 0);
  __syncthreads();

  const int last = tB;
  for (int kt = 0; kt <= last; kt++) {
    int cur = kt & 1;
    if (kt < last) stage(cur ^ 1, (kt + 1) * 64);
    const char* kld = kvs[cur][0];
    const char* vld = kvs[cur][1];
    int kv0 = kt * 64;
    if (kt <= tA) tile_step(qfA, oA, mA, lA, q0A, kv0, kld, vld, P[wid], la, lb);
    tile_step(qfB, oB, mB, lB, q0B, kv0, kld, vld, P[wid], la, lb);
    __syncthreads();
  }

#pragma unroll
  for (int r = 0; r < 4; r++) { mA[r] = 1.f / lA[r]; mB[r] = 1.f / lB[r]; }
#pragma unroll
  for (int df = 0; df < 8; df++)
#pragma unroll
    for (int r = 0; r < 4; r++) {
      int d = df * 16 + la;
      AO[(size_t)(q0A + lb * 4 + r) * H + h * D + d] = __float2bfloat16(oA[df][r] * mA[r]);
      AO[(size_t)(q0B + lb * 4 + r) * H + h * D + d] = __float2bfloat16(oB[df][r] * mB[r]);
    }
}

extern "C" void kernel_launch(void* const* d_in, const int* in_sizes, int n_in,
                              void* d_out, int out_size, void* d_ws, size_t ws_size,
                              hipStream_t stream) {
  const float*    X      = (const float*)d_in[0];
  const unsigned* qw_qkv = (const unsigned*)d_in[1];
  const unsigned* qz_qkv = (const unsigned*)d_in[2];
  const float*    sc_qkv = (const float*)d_in[3];
  const unsigned* qw_o   = (const unsigned*)d_in[4];
  const unsigned* qz_o   = (const unsigned*)d_in[5];
  const float*    sc_o   = (const float*)d_in[6];
  float* out = (float*)d_out;

  if (ws_size < 168820736ULL) return;
  char* ws = (char*)d_ws;
  bf16*   Wt = (bf16*)(ws);
  bf16*   Xb = (bf16*)(ws + 100663296);
  bf16*   Qv = (bf16*)(ws + 117440512);
  bf16*   Kv = (bf16*)(ws + 134217728);
  bf16*   VT = (bf16*)(ws + 150994944);
  float2* rt = (float2*)(ws + 167772160);
  bf16*   AO = Xb;

  k_rope_table<<<512, 256, 0, stream>>>(rt);
  k_cast_x<<<(S * H / 4) / 256, 256, 0, stream>>>((const float4*)X, (short4v*)Xb);
  k_dequant<<<(512 * 12288) / 256, 256, 0, stream>>>(qw_qkv, qz_qkv, sc_qkv, Wt, 12288, 4096);
  k_gemm8<0><<<768, 512, 0, stream>>>(Xb, Wt, 4096, 12288, nullptr, Qv, Kv, VT, rt, 8);
  k_dequant<<<(512 * 4096) / 256, 256, 0, stream>>>(qw_o, qz_o, sc_o, Wt, 4096, 4096);
  k_attn<<<dim3(16, 32), 256, 0, stream>>>(Qv, Kv, VT, AO);
  k_gemm8<1><<<256, 512, 0, stream>>>(AO, Wt, 4096, 4096, out, nullptr, nullptr, nullptr, nullptr, 8);
}

// Round 7
// 430.437 us; speedup vs baseline: 1.2203x; 1.0713x over previous
//
#include <hip/hip_runtime.h>
#include <hip/hip_bf16.h>
#include <cstdint>
#include <cstddef>

using bf16 = __hip_bfloat16;
typedef __attribute__((ext_vector_type(8))) short short8;
typedef __attribute__((ext_vector_type(4))) short short4v;
typedef __attribute__((ext_vector_type(4))) float f32x4;

#define MFMA16(a,b,c) __builtin_amdgcn_mfma_f32_16x16x32_bf16((a),(b),(c),0,0,0)
#define VMWAIT(n) asm volatile("s_waitcnt vmcnt(" #n ")" ::: "memory")

constexpr int S  = 2048;
constexpr int H  = 4096;
constexpr int D  = 128;

static __device__ __forceinline__ short bfbits(float f) {
  bf16 b = __float2bfloat16(f);
  return __builtin_bit_cast(short, b);
}

static __device__ __forceinline__ void gload16(const void* g, void* l) {
  __builtin_amdgcn_global_load_lds((const __attribute__((address_space(1))) void*)g,
                                   (__attribute__((address_space(3))) void*)l, 16, 0, 0);
}

// ---------------- RoPE cos/sin table: [S][64] float2 ----------------
__global__ void k_rope_table(float2* __restrict__ rt) {
  int tid = blockIdx.x * 256 + threadIdx.x;     // S*64 = 131072
  if (tid >= S * 64) return;
  int s = tid >> 6, j = tid & 63;
  float inv = exp2f(-(float)j * (13.287712379549449f / 64.f)); // 10000^(-j/64)
  float a = (float)s * inv;
  rt[tid] = make_float2(cosf(a), sinf(a));
}

// ---------------- cast hidden fp32 -> bf16 ----------------
__global__ void k_cast_x(const float4* __restrict__ x, short4v* __restrict__ xb) {
  int tid = blockIdx.x * 256 + threadIdx.x;     // S*H/4
  float4 v = x[tid];
  short4v o = { bfbits(v.x), bfbits(v.y), bfbits(v.z), bfbits(v.w) };
  xb[tid] = o;
}

// ---------------- GPTQ int4 dequant -> W^T bf16 [N][K] ----------------
__global__ void k_dequant(const unsigned* __restrict__ qw, const unsigned* __restrict__ qz,
                          const float* __restrict__ sc, bf16* __restrict__ wt,
                          int N, int K) {
  long tid = (long)blockIdx.x * 256 + threadIdx.x;   // over (K/8) * N
  if (tid >= (long)(K >> 3) * N) return;
  int k8 = (int)(tid / N);
  int n  = (int)(tid % N);
  int g  = k8 >> 4;                      // (k8*8)/128
  unsigned q  = qw[tid];                 // qweight[k8][n]
  unsigned zq = qz[g * (N >> 3) + (n >> 3)];
  float z = (float)(((zq >> ((n & 7) * 4)) & 15u) + 1u);
  float s = sc[g * N + n];
  short8 o;
#pragma unroll
  for (int i = 0; i < 8; i++) {
    float w = (float)((q >> (4 * i)) & 15u);
    o[i] = bfbits((w - z) * s);
  }
  *(short8*)&wt[(size_t)n * K + (k8 << 3)] = o;
}

// ---------------- pipelined bf16 MFMA GEMM (frag-prefetch schedule) --------
// C[M,N] = A[M,K] @ Bt[N,K]^T.  BM=256, BN=128, BK=64, 512 thr = 8 waves
// (4 wr x 2 wc), wave tile 64x64.  3 LDS buffers (144 KB), stage lookahead
// 2 K-tiles.  Fragment ds_reads are issued ONE PHASE AHEAD (register
// double-buffer) so MFMA never waits on LDS; 1 barrier + 1 counted vmcnt
// per K-tile (never 0 mid-loop).  Row-chunk XOR swizzle with inverse on the
// global source (gload_lds dest stays linear).
template<int EPI>
__global__ __launch_bounds__(512, 2)
void k_gemm8(const bf16* __restrict__ A, const bf16* __restrict__ Bt, int K, int N,
             float* __restrict__ outf,
             bf16* __restrict__ Qv, bf16* __restrict__ Kv, bf16* __restrict__ VT,
             const float2* __restrict__ rope, int nby)
{
  __shared__ __align__(16) bf16 sA[3][256 * 64];   // 96 KB
  __shared__ __align__(16) bf16 sB[3][128 * 64];   // 48 KB

  const int t = threadIdx.x;
  const int wid = t >> 6, lane = t & 63;
  const int la = lane & 15, lb = lane >> 4;
  const int wr = wid >> 1, wc = wid & 1;

  const int nwg  = gridDim.x;
  const int bid  = blockIdx.x;
  const int wgid = (bid & 7) * (nwg >> 3) + (bid >> 3);   // bijective (nwg%8==0)
  const int by = wgid % nby, bx = wgid / nby;             // col-major: B-panel sharing
  const int m0 = by * 256, n0 = bx * 128;

  // staging: thread t covers row (t>>3) of a 64-row group, 16B chunk (t&7);
  // global chunk pre-swizzled by row&7 so LDS stays linear for gload_lds.
  const int srow = t >> 3;
  const int scol = ((t & 7) ^ (srow & 7)) * 8;            // element offset
  const bf16* gA = A  + (size_t)(m0 + srow) * K + scol;
  const bf16* gB = Bt + (size_t)(n0 + srow) * K + scol;

  const int NT = K >> 6;                                  // BK=64

  // stage one half (h=0: A rows 0..127 + B rows 0..63; h=1: the rest) = 3 loads
  auto stageH = [&](int tile, int buf, int h) {
    const bf16* a = gA + tile * 64 + (size_t)(h * 128) * K;
    gload16(a,                  &sA[buf][h * 8192] + t * 8);
    gload16(a + (size_t)64 * K, &sA[buf][h * 8192 + 4096] + t * 8);
    const bf16* b = gB + tile * 64 + (size_t)(h * 64) * K;
    gload16(b, &sB[buf][h * 4096] + t * 8);
  };

  const char* const cA = (const char*)&sA[0][0];
  const char* const cB = (const char*)&sB[0][0];

  // fragment readers: kh = k-half of the BK=64 tile
  auto rdA = [&](short8 (&f)[4], const char* bA, int kh) {
    const int colb = ((kh * 4 + lb) ^ (la & 7)) * 16;
#pragma unroll
    for (int mf = 0; mf < 4; mf++)
      f[mf] = *(const short8*)(bA + (wr * 64 + mf * 16 + la) * 128 + colb);
  };
  auto rdB = [&](short8 (&f)[4], const char* bB, int kh) {
    const int colb = ((kh * 4 + lb) ^ (la & 7)) * 16;
#pragma unroll
    for (int nf = 0; nf < 4; nf++)
      f[nf] = *(const short8*)(bB + (wc * 64 + nf * 16 + la) * 128 + colb);
  };

  f32x4 acc[4][4] = {};
  short8 fa0[4], fb0[4], fa1[4], fb1[4];

  stageH(0, 0, 0); stageH(0, 0, 1);
  stageH(1, 1, 0); stageH(1, 1, 1);
  VMWAIT(6);                                 // tile 0 landed (6 newest = tile 1)
  __builtin_amdgcn_s_barrier();

  int cb0 = 0, cb1 = 1, cb2 = 2;
  rdA(fa0, cA, 0); rdB(fb0, cB, 0);          // frags(tile0, kh0)

  for (int tt = 0; tt < NT; tt++) {
    const char* pA = cA + cb0 * 32768;
    const char* pB = cB + cb0 * 16384;
    // ---- phase A: prefetch kh1 frags, stage half 0, MFMA kh0 ----
    rdA(fa1, pA, 1); rdB(fb1, pB, 1);
    if (tt + 2 < NT) stageH(tt + 2, cb2, 0);
    __builtin_amdgcn_s_setprio(1);
#pragma unroll
    for (int mf = 0; mf < 4; mf++)
#pragma unroll
      for (int nf = 0; nf < 4; nf++)
        acc[mf][nf] = MFMA16(fa0[mf], fb0[nf], acc[mf][nf]);
    __builtin_amdgcn_s_setprio(0);
    // ---- phase B: make next tile visible, prefetch its kh0 frags, MFMA kh1 --
    if (tt + 1 < NT) {
      if (tt + 2 < NT) VMWAIT(3); else VMWAIT(0);
      __builtin_amdgcn_s_barrier();
      const char* nA = cA + cb1 * 32768;
      const char* nB = cB + cb1 * 16384;
      rdA(fa0, nA, 0); rdB(fb0, nB, 0);
    }
    if (tt + 2 < NT) stageH(tt + 2, cb2, 1);
    __builtin_amdgcn_s_setprio(1);
#pragma unroll
    for (int mf = 0; mf < 4; mf++)
#pragma unroll
      for (int nf = 0; nf < 4; nf++)
        acc[mf][nf] = MFMA16(fa1[mf], fb1[nf], acc[mf][nf]);
    __builtin_amdgcn_s_setprio(0);
    int tmp = cb0; cb0 = cb1; cb1 = cb2; cb2 = tmp;
  }

  if constexpr (EPI == 1) {
#pragma unroll
    for (int mf = 0; mf < 4; mf++)
#pragma unroll
      for (int nf = 0; nf < 4; nf++)
#pragma unroll
        for (int r = 0; r < 4; r++) {
          int row = m0 + wr * 64 + mf * 16 + lb * 4 + r;
          int col = n0 + wc * 64 + nf * 16 + la;
          outf[(size_t)row * N + col] = acc[mf][nf][r];
        }
  } else {
    const int typ = n0 >> 12;              // block = exactly one 128-col head
    const int h   = (n0 & 4095) >> 7;
    if (typ == 2) {
      bf16* dst = VT + (size_t)h * D * S;  // [d][s]
#pragma unroll
      for (int mf = 0; mf < 4; mf++)
#pragma unroll
        for (int nf = 0; nf < 4; nf++) {
          int d  = wc * 64 + nf * 16 + la;
          int s0 = m0 + wr * 64 + mf * 16 + lb * 4;
          short4v o = { bfbits(acc[mf][nf][0]), bfbits(acc[mf][nf][1]),
                        bfbits(acc[mf][nf][2]), bfbits(acc[mf][nf][3]) };
          *(short4v*)&dst[(size_t)d * S + s0] = o;
        }
    } else {
      // RoPE needs (d, d+64) pairs which live in different waves:
      // exchange the whole 256x128 tile through the (now free) staging LDS.
      bf16* dst = (typ == 0 ? Qv : Kv) + (size_t)h * S * D;
      bf16* xs = (bf16*)&sA[0][0];         // [256][128] bf16 = 64 KB
      __syncthreads();
#pragma unroll
      for (int mf = 0; mf < 4; mf++)
#pragma unroll
        for (int nf = 0; nf < 4; nf++)
#pragma unroll
          for (int r = 0; r < 4; r++)
            xs[(wr * 64 + mf * 16 + lb * 4 + r) * 128 + wc * 64 + nf * 16 + la] =
                __float2bfloat16(acc[mf][nf][r]);
      __syncthreads();
#pragma unroll 4
      for (int w = 0; w < 32; w++) {
        int idx = w * 512 + t;             // 256 rows x 64 d-pairs
        int row = idx >> 6, dp = idx & 63;
        float x  = __bfloat162float(xs[row * 128 + dp]);
        float xp = __bfloat162float(xs[row * 128 + dp + 64]);
        float2 cs = rope[(size_t)(m0 + row) * 64 + dp];
        dst[(size_t)(m0 + row) * D + dp]      = __float2bfloat16(x * cs.x - xp * cs.y);
        dst[(size_t)(m0 + row) * D + dp + 64] = __float2bfloat16(xp * cs.x + x * cs.y);
      }
    }
  }
}

// ---------------- causal flash attention, paired q-tiles + LDS KV pipeline ----
__device__ __forceinline__ void tile_step(
    const short8 (&qf)[4], f32x4 (&o)[8], float (&mrow)[4], float (&lrow)[4],
    int q0t, int kv0, const char* kld, const char* vld,
    bf16 (*Pw)[72], int la, int lb)
{
  const float smscale = 0.08838834764831845f;   // 1/sqrt(128)
  f32x4 sv[4] = {};
  __builtin_amdgcn_s_setprio(1);
#pragma unroll
  for (int ks = 0; ks < 4; ks++) {
#pragma unroll
    for (int kf = 0; kf < 4; kf++) {
      int row = kf * 16 + la;
      short8 kb = *(const short8*)(kld + row * 256 + ((ks * 64 + lb * 16) ^ ((row & 7) << 4)));
      sv[kf] = MFMA16(qf[ks], kb, sv[kf]);
    }
  }
  __builtin_amdgcn_s_setprio(0);
  const bool needmask = (kv0 + 63 > q0t);
#pragma unroll
  for (int kf = 0; kf < 4; kf++)
#pragma unroll
    for (int r = 0; r < 4; r++) {
      float v = sv[kf][r] * smscale;
      if (needmask && (kv0 + kf * 16 + la > q0t + lb * 4 + r)) v = -1e30f;
      sv[kf][r] = v;
    }
  float mnew[4], csc[4], rs[4];
#pragma unroll
  for (int r = 0; r < 4; r++)
    mnew[r] = fmaxf(fmaxf(sv[0][r], sv[1][r]), fmaxf(sv[2][r], sv[3][r]));
#pragma unroll
  for (int off = 1; off < 16; off <<= 1)
#pragma unroll
    for (int r = 0; r < 4; r++) mnew[r] = fmaxf(mnew[r], __shfl_xor(mnew[r], off));
#pragma unroll
  for (int r = 0; r < 4; r++) {
    float mt = fmaxf(mrow[r], mnew[r]);
    csc[r] = __expf(mrow[r] - mt);
    mrow[r] = mt;
    rs[r] = 0.f;
  }
#pragma unroll
  for (int kf = 0; kf < 4; kf++)
#pragma unroll
    for (int r = 0; r < 4; r++) {
      float p = __expf(sv[kf][r] - mrow[r]);
      sv[kf][r] = p;
      rs[r] += p;
    }
#pragma unroll
  for (int off = 1; off < 16; off <<= 1)
#pragma unroll
    for (int r = 0; r < 4; r++) rs[r] += __shfl_xor(rs[r], off);
#pragma unroll
  for (int r = 0; r < 4; r++) lrow[r] = lrow[r] * csc[r] + rs[r];
#pragma unroll
  for (int df = 0; df < 8; df++)
#pragma unroll
    for (int r = 0; r < 4; r++) o[df][r] *= csc[r];
#pragma unroll
  for (int kf = 0; kf < 4; kf++)
#pragma unroll
    for (int r = 0; r < 4; r++)
      Pw[lb * 4 + r][kf * 16 + la] = __float2bfloat16(sv[kf][r]);
  asm volatile("s_waitcnt lgkmcnt(0)" ::: "memory");
  __builtin_amdgcn_sched_barrier(0);
  short8 pa0 = *(const short8*)&Pw[la][lb * 8];
  short8 pa1 = *(const short8*)&Pw[la][32 + lb * 8];
  __builtin_amdgcn_s_setprio(1);
#pragma unroll
  for (int df = 0; df < 8; df++) {
    int d = df * 16 + la;
    short8 vb0 = *(const short8*)(vld + d * 128 + ((lb * 16) ^ ((d & 7) << 4)));
    o[df] = MFMA16(pa0, vb0, o[df]);
    short8 vb1 = *(const short8*)(vld + d * 128 + ((64 + lb * 16) ^ ((d & 7) << 4)));
    o[df] = MFMA16(pa1, vb1, o[df]);
  }
  __builtin_amdgcn_s_setprio(0);
}

__global__ __launch_bounds__(256, 2)
void k_attn(const bf16* __restrict__ Qv, const bf16* __restrict__ Kvp,
            const bf16* __restrict__ VT, bf16* __restrict__ AO)
{
  __shared__ __align__(16) char kvs[2][2][16384];   // [dbuf][K/V]
  __shared__ __align__(16) bf16 P[4][16][72];
  const int t = threadIdx.x, wid = t >> 6, lane = t & 63;
  const int la = lane & 15, lb = lane >> 4;
  const int h = blockIdx.y, ip = blockIdx.x;         // 0..15
  const int tA = ip, tB = 31 - ip;
  const int q0A = tA * 64 + wid * 16, q0B = tB * 64 + wid * 16;
  const bf16* Qh = Qv  + (size_t)h * S * D;
  const bf16* Kh = Kvp + (size_t)h * S * D;
  const bf16* Vh = VT  + (size_t)h * D * S;

  short8 qfA[4], qfB[4];
#pragma unroll
  for (int ks = 0; ks < 4; ks++) {
    qfA[ks] = *(const short8*)&Qh[(size_t)(q0A + la) * D + ks * 32 + lb * 8];
    qfB[ks] = *(const short8*)&Qh[(size_t)(q0B + la) * D + ks * 32 + lb * 8];
  }

  f32x4 oA[8] = {}, oB[8] = {};
  float mA[4] = {-1e30f, -1e30f, -1e30f, -1e30f}, lA[4] = {};
  float mB[4] = {-1e30f, -1e30f, -1e30f, -1e30f}, lB[4] = {};

  auto stage = [&](int buf, int kv0) {
#pragma unroll
    for (int i = 0; i < 4; i++) {
      int off = i * 4096 + wid * 1024 + lane * 16;
      int krow = off >> 8, kcol = off & 255;
      const char* ksrc = (const char*)Kh + (size_t)(kv0 + krow) * 256 + (kcol ^ ((krow & 7) << 4));
      gload16(ksrc, &kvs[buf][0][i * 4096 + wid * 1024]);
      int vrow = off >> 7, vcol = off & 127;
      const char* vsrc = (const char*)Vh + (size_t)vrow * (S * 2) + kv0 * 2 + (vcol ^ ((vrow & 7) << 4));
      gload16(vsrc, &kvs[buf][1][i * 4096 + wid * 1024]);
    }
  };

  stage(0, 0);
  __syncthreads();

  const int last = tB;
  for (int kt = 0; kt <= last; kt++) {
    int cur = kt & 1;
    if (kt < last) stage(cur ^ 1, (kt + 1) * 64);
    const char* kld = kvs[cur][0];
    const char* vld = kvs[cur][1];
    int kv0 = kt * 64;
    if (kt <= tA) tile_step(qfA, oA, mA, lA, q0A, kv0, kld, vld, P[wid], la, lb);
    tile_step(qfB, oB, mB, lB, q0B, kv0, kld, vld, P[wid], la, lb);
    __syncthreads();
  }

#pragma unroll
  for (int r = 0; r < 4; r++) { mA[r] = 1.f / lA[r]; mB[r] = 1.f / lB[r]; }
#pragma unroll
  for (int df = 0; df < 8; df++)
#pragma unroll
    for (int r = 0; r < 4; r++) {
      int d = df * 16 + la;
      AO[(size_t)(q0A + lb * 4 + r) * H + h * D + d] = __float2bfloat16(oA[df][r] * mA[r]);
      AO[(size_t)(q0B + lb * 4 + r) * H + h * D + d] = __float2bfloat16(oB[df][r] * mB[r]);
    }
}

extern "C" void kernel_launch(void* const* d_in, const int* in_sizes, int n_in,
                              void* d_out, int out_size, void* d_ws, size_t ws_size,
                              hipStream_t stream) {
  const float*    X      = (const float*)d_in[0];
  const unsigned* qw_qkv = (const unsigned*)d_in[1];
  const unsigned* qz_qkv = (const unsigned*)d_in[2];
  const float*    sc_qkv = (const float*)d_in[3];
  const unsigned* qw_o   = (const unsigned*)d_in[4];
  const unsigned* qz_o   = (const unsigned*)d_in[5];
  const float*    sc_o   = (const float*)d_in[6];
  float* out = (float*)d_out;

  if (ws_size < 168820736ULL) return;
  char* ws = (char*)d_ws;
  bf16*   Wt = (bf16*)(ws);
  bf16*   Xb = (bf16*)(ws + 100663296);
  bf16*   Qv = (bf16*)(ws + 117440512);
  bf16*   Kv = (bf16*)(ws + 134217728);
  bf16*   VT = (bf16*)(ws + 150994944);
  float2* rt = (float2*)(ws + 167772160);
  bf16*   AO = Xb;

  k_rope_table<<<512, 256, 0, stream>>>(rt);
  k_cast_x<<<(S * H / 4) / 256, 256, 0, stream>>>((const float4*)X, (short4v*)Xb);
  k_dequant<<<(512 * 12288) / 256, 256, 0, stream>>>(qw_qkv, qz_qkv, sc_qkv, Wt, 12288, 4096);
  k_gemm8<0><<<768, 512, 0, stream>>>(Xb, Wt, 4096, 12288, nullptr, Qv, Kv, VT, rt, 8);
  k_dequant<<<(512 * 4096) / 256, 256, 0, stream>>>(qw_o, qz_o, sc_o, Wt, 4096, 4096);
  k_attn<<<dim3(16, 32), 256, 0, stream>>>(Qv, Kv, VT, AO);
  k_gemm8<1><<<256, 512, 0, stream>>>(AO, Wt, 4096, 4096, out, nullptr, nullptr, nullptr, nullptr, 8);
}